// Round 2
// baseline (301.528 us; speedup 1.0000x reference)
//
#include <hip/hip_runtime.h>

// out[b,d] = sum_{j=0..x-1} hidden[b, start+j, d]
// start = clamp(sum(mask[B-1,:]) - x, 0, S-x)   (lax.dynamic_slice clamping)
//
// Single-launch, atomic-free, memset-free version.
// Block = 256 threads = 4 waves (JQ=4). Each block owns (b, 64-wide float4
// d-tile). Wave w sums window rows j in [w*chunk, min((w+1)*chunk, x)) for its
// 64 d4 lanes (coalesced 1 KB wave-loads). Partials combine through 4 KB LDS;
// the first 64 threads write each output float4 exactly once -> the 0xAA
// poison in d_out is fully overwritten, no hipMemsetAsync needed.
// Each block still redundantly reduces the last mask row (8 KB int32, L2-hot)
// to get `start` without a separate kernel.
#define JQ 4

__global__ __launch_bounds__(256) void srs_window_sum(
    const float4* __restrict__ hidden,
    const int* __restrict__ mask,
    const int* __restrict__ xp,
    float4* __restrict__ out,
    int B, int S, int D4, int ntile)
{
    __shared__ int s_wave[JQ];
    __shared__ int s_start;
    __shared__ float4 s_part[256];

    const int tid  = threadIdx.x;
    const int lane = tid & 63;
    const int w    = tid >> 6;
    const int x    = *xp;

    // --- per-block mask-row sum (row B-1), int4-vectorized ---
    int acc = 0;
    const int* mrow = mask + (size_t)(B - 1) * S;
    if ((S & 3) == 0) {
        const int4* m4 = (const int4*)mrow;
        const int S4 = S >> 2;
        for (int i = tid; i < S4; i += 256) {
            int4 v = m4[i];
            acc += v.x + v.y + v.z + v.w;
        }
    } else {
        for (int i = tid; i < S; i += 256) acc += mrow[i];
    }
    #pragma unroll
    for (int off = 32; off > 0; off >>= 1) acc += __shfl_down(acc, off, 64);
    if (lane == 0) s_wave[w] = acc;
    __syncthreads();
    if (tid == 0) {
        int length = s_wave[0] + s_wave[1] + s_wave[2] + s_wave[3];
        int start = length - x;
        if (start < 0) start = 0;
        if (start > S - x) start = S - x;
        s_start = start;
    }
    __syncthreads();
    const int start = s_start;

    // --- windowed partial sum: wave w covers its j-chunk for 64 d4 lanes ---
    const int b    = blockIdx.x / ntile;
    const int tile = blockIdx.x - b * ntile;
    const int d4   = tile * 64 + lane;

    const int chunk = (x + JQ - 1) / JQ;
    const int j0 = w * chunk;
    int j1 = j0 + chunk; if (j1 > x) j1 = x;

    float4 s = make_float4(0.f, 0.f, 0.f, 0.f);
    if (d4 < D4) {
        const float4* p = hidden + ((size_t)b * S + (size_t)start) * D4 + d4;
        for (int j = j0; j < j1; ++j) {
            float4 h = p[(size_t)j * D4];   // 64 lanes x 16 B = 1 KB coalesced
            s.x += h.x; s.y += h.y; s.z += h.z; s.w += h.w;
        }
    }
    s_part[tid] = s;
    __syncthreads();

    // --- cross-wave combine + single clean store (full output coverage) ---
    if (tid < 64) {
        float4 a = s_part[tid];
        float4 b1 = s_part[tid + 64];
        float4 c = s_part[tid + 128];
        float4 d1 = s_part[tid + 192];
        float4 r;
        r.x = a.x + b1.x + c.x + d1.x;
        r.y = a.y + b1.y + c.y + d1.y;
        r.z = a.z + b1.z + c.z + d1.z;
        r.w = a.w + b1.w + c.w + d1.w;
        if (d4 < D4) out[(size_t)b * D4 + d4] = r;
    }
}

extern "C" void kernel_launch(void* const* d_in, const int* in_sizes, int n_in,
                              void* d_out, int out_size, void* d_ws, size_t ws_size,
                              hipStream_t stream) {
    const float* hidden = (const float*)d_in[0];
    const int*   mask   = (const int*)d_in[1];
    const int*   xp     = (const int*)d_in[2];
    float4*      out    = (float4*)d_out;

    const long long nhid  = in_sizes[0];  // B*S*D
    const long long nmask = in_sizes[1];  // B*S
    const int D  = (int)(nhid / nmask);
    const int S  = (int)(nhid / (long long)out_size);  // (B*S*D)/(B*D)
    const int B  = out_size / D;
    const int D4 = D / 4;

    const int ntile = (D4 + 63) / 64;   // 64-float4-wide d-tiles per batch row
    dim3 grid(B * ntile);               // every (b,d4) covered exactly once
    srs_window_sum<<<grid, 256, 0, stream>>>(
        (const float4*)hidden, mask, xp, out, B, S, D4, ntile);
}